// Round 2
// baseline (835.044 us; speedup 1.0000x reference)
//
#include <hip/hip_runtime.h>
#include <math.h>

// DoG seasonal: out[b,l,c] = (k1*x)(l) - (k2*x)(l), depthwise over c, reflect pad.
// k1: sigma=4.2 (35 taps) exact. k2: sigma=96 (769 taps) via Gaussian pyramid:
//   G96 = G12 * G95.25 ; stage A: d[j] = (G12*x)(16j) (97 taps, decimate by 16)
//   stage B: e = gb * d on coarse grid (49 taps, sigma 95.25/16)
//   stage C (narrow): exact 35-tap conv + linear interp of e + subtract.
// Aliasing from stride-16 decimation after G12: worst-case fold amplitude ~2e-5.
// Interp error measured at ~0.008 absmax in round 1 (threshold 0.0266).

#define Bdim 32
#define Ldim 4096
#define Cdim 321

#define R1 17
#define K1n 35
#define R2 384
#define K2n 769

#define GA_R 48
#define GA_N 97          // sigma_a = 12
#define GB_R 24
#define GB_N 49          // sigma_b = sqrt(96^2-12^2)/16 on coarse grid

#define NG 257           // e grid: j = 0..256 at l = 16j
#define NJD 305          // d grid: jj = -24..280 stored at jj+24
#define NGRP_A 20        // stage A: groups of 16 d-points
#define NSEG 128         // narrow: segments of 32 outputs
#define NTJ 33           // stage B: groups of 8 outputs

// workspace float offsets
#define GA_OFF 0
#define GB_OFF 128
#define W1_OFF 192
#define K2_OFF 256       // 769 linear taps (naive fallback)
#define K2P_OFF 1088     // 784 polyphase-padded taps (middle fallback)
#define E2_OFF 4096      // middle-path e grid
#define D_OFF 4096       // pyramid d grid
#define E_OFF (D_OFF + Bdim*NJD*Cdim)            // 4096 + 3,132,960
#define WS_TOT (E_OFF + Bdim*NG*Cdim)            // + 2,639,904 floats

__device__ __forceinline__ int mirror_idx(int a) {
    a = a < 0 ? -a : a;
    a = a > (Ldim - 1) ? 2 * (Ldim - 1) - a : a;
    return a;
}

__device__ __forceinline__ int xcd_swizzle(int bid, int nwg) {
    // bijective XCD-chunk remap (m204): consecutive logical ids land on one XCD
    int q = nwg >> 3, r = nwg & 7;
    int xcd = bid & 7, i = bid >> 3;
    int base = (xcd < r) ? xcd * (q + 1) : r * (q + 1) + (xcd - r) * q;
    return base + i;
}

__device__ __forceinline__ float block_sum_1024(float v, float* partial) {
#pragma unroll
    for (int off = 32; off >= 1; off >>= 1) v += __shfl_down(v, off, 64);
    __syncthreads();                 // protect partial[] from previous use
    if ((threadIdx.x & 63) == 0) partial[threadIdx.x >> 6] = v;
    __syncthreads();
    float s = partial[0];
#pragma unroll
    for (int i = 1; i < 16; ++i) s += partial[i];
    return s;
}

__global__ void init_weights_kernel(float* __restrict__ w) {
    __shared__ float partial[16];
    const int tid = threadIdx.x;  // 1024 threads

    // ga: sigma 12, radius 48
    {
        float v = 0.f;
        if (tid < GA_N) { float t = (float)(tid - GA_R) * (1.0f / 12.0f); v = expf(-0.5f * t * t); }
        float s = block_sum_1024(v, partial);
        if (tid < GA_N) w[GA_OFF + tid] = v / s;
    }
    // gb: sigma sqrt(96^2-12^2)/16, radius 24
    {
        const float sb = sqrtf(96.f * 96.f - 12.f * 12.f) * (1.0f / 16.0f);
        float v = 0.f;
        if (tid < GB_N) { float t = (float)(tid - GB_R) / sb; v = expf(-0.5f * t * t); }
        float s = block_sum_1024(v, partial);
        if (tid < GB_N) w[GB_OFF + tid] = v / s;
    }
    // w1: sigma 4.2, radius 17
    {
        float v = 0.f;
        if (tid < K1n) { float t = (float)(tid - R1) * (1.0f / 4.2f); v = expf(-0.5f * t * t); }
        float s = block_sum_1024(v, partial);
        if (tid < K1n) w[W1_OFF + tid] = v / s;
    }
    // k2: sigma 96, radius 384 (fallback paths)
    {
        float v = 0.f;
        if (tid < K2n) { float t = (float)(tid - R2) * (1.0f / 96.0f); v = expf(-0.5f * t * t); }
        float s = block_sum_1024(v, partial);
        if (tid < K2n) w[K2_OFF + tid] = v / s;
        if (tid < 784) w[K2P_OFF + tid] = (tid < K2n) ? v / s : 0.f;
    }
}

// ---- Stage A: d[b, jj+24, c] = sum_t ga[t] * x~[16*jj - 48 + t], jj in [-24,280]
// polyphase over p = t mod 16; 16 d-points per thread, streaming row window.
__global__ __launch_bounds__(256) void decimA_kernel(
        const float* __restrict__ x, const float* __restrict__ ga,
        float* __restrict__ d) {
    __shared__ float gs[GA_N];
    if (threadIdx.x < GA_N) gs[threadIdx.x] = ga[threadIdx.x];
    __syncthreads();

    const int lb = xcd_swizzle(blockIdx.x, gridDim.x);
    const int lin = lb * 256 + threadIdx.x;
    const int c = lin % Cdim;
    const int rest = lin / Cdim;
    const int g = rest % NGRP_A;
    const int b = rest / NGRP_A;
    if (b >= Bdim) return;

    const int jj0 = -24 + 16 * g;
    const float* xb = x + b * (Ldim * Cdim) + c;

    float acc[16];
#pragma unroll
    for (int ii = 0; ii < 16; ++ii) acc[ii] = 0.f;

    const bool interior = (jj0 >= 3) && (jj0 <= 237);

#pragma unroll 1
    for (int p = 0; p < 16; ++p) {
        float row[22];
        if (interior) {
            const float* xp = xb + (16 * (jj0 - 3) + p) * Cdim;
#pragma unroll
            for (int i = 0; i < 22; ++i) row[i] = xp[i * (16 * Cdim)];
        } else {
#pragma unroll
            for (int i = 0; i < 22; ++i)
                row[i] = xb[mirror_idx(16 * (jj0 - 3 + i) + p) * Cdim];
        }
#pragma unroll
        for (int q = 0; q < 6; ++q) {
            const float wq = gs[16 * q + p];
#pragma unroll
            for (int ii = 0; ii < 16; ++ii)
                acc[ii] = fmaf(wq, row[ii + q], acc[ii]);
        }
        if (p == 0) {  // tap t=96 exists only for phase 0
            const float w6 = gs[96];
#pragma unroll
            for (int ii = 0; ii < 16; ++ii)
                acc[ii] = fmaf(w6, row[ii + 6], acc[ii]);
        }
    }

    const int j0d = jj0 + 24;   // 0..304, multiple of 16
    float* db = d + (b * NJD + j0d) * Cdim + c;
#pragma unroll
    for (int ii = 0; ii < 16; ++ii)
        if (j0d + ii < NJD) db[ii * Cdim] = acc[ii];
}

// ---- Stage B: e[b, j, c] = sum_s gb[s] * d[b, j+s, c], j in [0,256]
__global__ __launch_bounds__(256) void coarseB_kernel(
        const float* __restrict__ d, const float* __restrict__ gb,
        float* __restrict__ e) {
    __shared__ float gbs[GB_N];
    if (threadIdx.x < GB_N) gbs[threadIdx.x] = gb[threadIdx.x];
    __syncthreads();

    const int lin = blockIdx.x * 256 + threadIdx.x;
    const int c = lin % Cdim;
    const int rest = lin / Cdim;
    const int tj = rest % NTJ;
    const int b = rest / NTJ;
    if (b >= Bdim) return;

    float wr[GB_N];
#pragma unroll
    for (int s = 0; s < GB_N; ++s) wr[s] = gbs[s];

    const int j0 = tj * 8;
    const float* db = d + b * (NJD * Cdim) + c;

    float acc[8];
#pragma unroll
    for (int jj = 0; jj < 8; ++jj) acc[jj] = 0.f;

#pragma unroll
    for (int r = 0; r < 56; ++r) {
        int idx = j0 + r;
        idx = idx > (NJD - 1) ? (NJD - 1) : idx;   // clamp for the tail group
        const float v = db[idx * Cdim];
        const int jlo = r - 48 > 0 ? r - 48 : 0;
        const int jhi = r < 7 ? r : 7;
#pragma unroll
        for (int jj = 0; jj < 8; ++jj)
            if (jj >= jlo && jj <= jhi)
                acc[jj] = fmaf(wr[r - jj], v, acc[jj]);
    }

    float* eb = e + (b * NG + j0) * Cdim + c;
#pragma unroll
    for (int jj = 0; jj < 8; ++jj)
        if (j0 + jj < NG) eb[jj * Cdim] = acc[jj];
}

// ---- Stage C: narrow conv (exact) + linear interp of e + subtract. 32 out/thread.
__global__ __launch_bounds__(256) void narrow_kernel(
        const float* __restrict__ x, const float* __restrict__ w1,
        const float* __restrict__ e, float* __restrict__ out) {
    __shared__ float ws[K1n];
    if (threadIdx.x < K1n) ws[threadIdx.x] = w1[threadIdx.x];
    __syncthreads();

    const int lb = xcd_swizzle(blockIdx.x, gridDim.x);
    const int lin = lb * 256 + threadIdx.x;
    const int c = lin % Cdim;
    const int rest = lin / Cdim;
    const int seg = rest % NSEG;
    const int b = rest / NSEG;
    if (b >= Bdim) return;

    float wr[K1n];
#pragma unroll
    for (int t = 0; t < K1n; ++t) wr[t] = ws[t];

    const int l0 = seg * 32;
    const float* xb = x + b * (Ldim * Cdim) + c;

    // issue the (L3-resident) e loads early
    const int j0 = seg * 2;
    const float* eb = e + (b * NG + j0) * Cdim + c;
    const float z0 = eb[0];
    const float z1 = eb[Cdim];
    const float z2 = eb[2 * Cdim];

    float acc[32];
#pragma unroll
    for (int m = 0; m < 32; ++m) acc[m] = 0.f;

    if (seg >= 1 && seg <= 126) {
        const float* xp = xb + (l0 - R1) * Cdim;
#pragma unroll
        for (int r = 0; r < 66; ++r) {
            const float v = xp[r * Cdim];
            const int tlo = r - 31 > 0 ? r - 31 : 0;
            const int thi = r < 34 ? r : 34;
#pragma unroll
            for (int t = 0; t < K1n; ++t)
                if (t >= tlo && t <= thi)
                    acc[r - t] = fmaf(wr[t], v, acc[r - t]);
        }
    } else {
#pragma unroll
        for (int r = 0; r < 66; ++r) {
            const float v = xb[mirror_idx(l0 - R1 + r) * Cdim];
            const int tlo = r - 31 > 0 ? r - 31 : 0;
            const int thi = r < 34 ? r : 34;
#pragma unroll
            for (int t = 0; t < K1n; ++t)
                if (t >= tlo && t <= thi)
                    acc[r - t] = fmaf(wr[t], v, acc[r - t]);
        }
    }

    const float d0 = (z1 - z0) * (1.0f / 16.0f);
    const float d1 = (z2 - z1) * (1.0f / 16.0f);
    float* ob = out + (b * Ldim + l0) * Cdim + c;
#pragma unroll
    for (int m = 0; m < 16; ++m)
        ob[m * Cdim] = acc[m] - fmaf(d0, (float)m, z0);
#pragma unroll
    for (int m = 16; m < 32; ++m)
        ob[m * Cdim] = acc[m] - fmaf(d1, (float)(m - 16), z1);
}

// ---- Middle fallback: direct 769-tap wide conv on the stride-16 grid (round-1)
#define JPT 16
#define NJG 17
__global__ __launch_bounds__(256, 2) void wide_mid_kernel(
        const float* __restrict__ x, const float* __restrict__ w2p,
        float* __restrict__ z) {
    __shared__ float w2s[784];
    for (int i = threadIdx.x; i < 784; i += 256) w2s[i] = w2p[i];
    __syncthreads();

    const int gid = blockIdx.x * 256 + threadIdx.x;
    const int c = gid % Cdim;
    const int rest = gid / Cdim;
    const int jg = rest % NJG;
    const int b = rest / NJG;
    if (b >= Bdim) return;

    const int j0 = jg * JPT;
    const float* xb = x + b * (Ldim * Cdim) + c;

    float acc[JPT];
#pragma unroll
    for (int jj = 0; jj < JPT; ++jj) acc[jj] = 0.f;

    const bool interior = (j0 >= 24) && (16 * (j0 + 39) + 15 <= Ldim - 1);

#pragma unroll 1
    for (int p = 0; p < 16; ++p) {
        float row[64];
        if (interior) {
            const float* xp = xb + (16 * (j0 - 24) + p) * Cdim;
#pragma unroll
            for (int i = 0; i < 64; ++i) row[i] = xp[i * (16 * Cdim)];
        } else {
#pragma unroll
            for (int i = 0; i < 64; ++i)
                row[i] = xb[mirror_idx(16 * (j0 - 24 + i) + p) * Cdim];
        }
#pragma unroll
        for (int q = 0; q < 49; ++q) {
            const float wq = w2s[q * 16 + p];
#pragma unroll
            for (int jj = 0; jj < JPT; ++jj)
                acc[jj] = fmaf(wq, row[q + jj], acc[jj]);
        }
    }

    float* zb = z + (b * NG + j0) * Cdim + c;
#pragma unroll
    for (int jj = 0; jj < JPT; ++jj)
        if (j0 + jj < NG) zb[jj * Cdim] = acc[jj];
}

// ---- Last-resort fallback: fully direct
__global__ __launch_bounds__(256) void naive_kernel(
        const float* __restrict__ x, const float* __restrict__ w,
        float* __restrict__ out) {
    const int gid = blockIdx.x * 256 + threadIdx.x;
    if (gid >= Bdim * Ldim * Cdim) return;
    const int c = gid % Cdim;
    const int rest = gid / Cdim;
    const int l = rest % Ldim;
    const int b = rest / Ldim;
    const float* xb = x + b * (Ldim * Cdim) + c;
    float a2 = 0.f, a1 = 0.f;
    for (int t = 0; t < K2n; ++t)
        a2 = fmaf(w[K2_OFF + t], xb[mirror_idx(l + t - R2) * Cdim], a2);
#pragma unroll
    for (int t = 0; t < K1n; ++t)
        a1 = fmaf(w[W1_OFF + t], xb[mirror_idx(l + t - R1) * Cdim], a1);
    out[gid] = a1 - a2;
}

extern "C" void kernel_launch(void* const* d_in, const int* in_sizes, int n_in,
                              void* d_out, int out_size, void* d_ws, size_t ws_size,
                              hipStream_t stream) {
    (void)in_sizes; (void)n_in; (void)out_size;
    const float* x = (const float*)d_in[0];
    float* out = (float*)d_out;
    float* w = (float*)d_ws;

    hipLaunchKernelGGL(init_weights_kernel, dim3(1), dim3(1024), 0, stream, w);

    const size_t need_pyr = (size_t)WS_TOT * sizeof(float);
    const size_t need_mid = (size_t)(E2_OFF + Bdim * NG * Cdim) * sizeof(float);

    const int nar_total = Bdim * NSEG * Cdim;          // 1,314,816
    const dim3 nar_grid((nar_total + 255) / 256);

    if (ws_size >= need_pyr) {
        const int a_total = Bdim * NGRP_A * Cdim;      // 205,440
        hipLaunchKernelGGL(decimA_kernel, dim3((a_total + 255) / 256), dim3(256),
                           0, stream, x, w + GA_OFF, w + D_OFF);
        const int b_total = Bdim * NTJ * Cdim;         // 338,976
        hipLaunchKernelGGL(coarseB_kernel, dim3((b_total + 255) / 256), dim3(256),
                           0, stream, w + D_OFF, w + GB_OFF, w + E_OFF);
        hipLaunchKernelGGL(narrow_kernel, nar_grid, dim3(256),
                           0, stream, x, w + W1_OFF, w + E_OFF, out);
    } else if (ws_size >= need_mid) {
        const int wide_total = Bdim * NJG * Cdim;      // 174,624
        hipLaunchKernelGGL(wide_mid_kernel, dim3((wide_total + 255) / 256), dim3(256),
                           0, stream, x, w + K2P_OFF, w + E2_OFF);
        hipLaunchKernelGGL(narrow_kernel, nar_grid, dim3(256),
                           0, stream, x, w + W1_OFF, w + E2_OFF, out);
    } else {
        const int total = Bdim * Ldim * Cdim;
        hipLaunchKernelGGL(naive_kernel, dim3((total + 255) / 256), dim3(256),
                           0, stream, x, w, out);
    }
}

// Round 3
// 150.431 us; speedup vs baseline: 5.5510x; 5.5510x over previous
//
#include <hip/hip_runtime.h>
#include <math.h>

// DoG seasonal: out[b,l,c] = (k1*x)(l) - (k2*x)(l), depthwise over c, reflect pad.
// k1: sigma=4.2 (35 taps) exact. k2: sigma=96 (769 taps) via Gaussian pyramid:
//   G96 = G12 * G95.25 ; stage A: d[j] = (G12*x)(16j) (97 taps, decimate by 16)
//   stage B: e = gb * d on coarse grid (49 taps)
//   stage C (narrow): exact 35-tap conv + linear interp of e + subtract.
// Round-2 lesson: narrow MUST use the gather form (static acc indexing);
// the scatter form went to scratch (VGPR=44, 790us). This restores round-1's
// structure at 32 outputs/thread.

#define Bdim 32
#define Ldim 4096
#define Cdim 321

#define R1 17
#define K1n 35
#define R2 384
#define K2n 769

#define GA_R 48
#define GA_N 97          // sigma_a = 12
#define GB_R 24
#define GB_N 49          // sigma_b = sqrt(96^2-12^2)/16 on coarse grid

#define NG 257           // e grid: j = 0..256 at l = 16j
#define NJD 305          // d grid: jj = -24..280 stored at jj+24
#define NGRP_A 20        // stage A: groups of 16 d-points
#define NSEG 128         // narrow: segments of 32 outputs
#define NTJ 33           // stage B: groups of 8 outputs

// workspace float offsets
#define GA_OFF 0
#define GB_OFF 128
#define W1_OFF 192
#define K2_OFF 256       // 769 linear taps (naive fallback)
#define K2P_OFF 1088     // 784 polyphase-padded taps (middle fallback)
#define E2_OFF 4096      // middle-path e grid
#define D_OFF 4096       // pyramid d grid
#define E_OFF (D_OFF + Bdim*NJD*Cdim)            // 4096 + 3,132,960
#define WS_TOT (E_OFF + Bdim*NG*Cdim)            // + 2,639,904 floats

__device__ __forceinline__ int mirror_idx(int a) {
    a = a < 0 ? -a : a;
    a = a > (Ldim - 1) ? 2 * (Ldim - 1) - a : a;
    return a;
}

__device__ __forceinline__ int xcd_swizzle(int bid, int nwg) {
    // bijective XCD-chunk remap (m204): consecutive logical ids land on one XCD
    int q = nwg >> 3, r = nwg & 7;
    int xcd = bid & 7, i = bid >> 3;
    int base = (xcd < r) ? xcd * (q + 1) : r * (q + 1) + (xcd - r) * q;
    return base + i;
}

__device__ __forceinline__ float block_sum_1024(float v, float* partial) {
#pragma unroll
    for (int off = 32; off >= 1; off >>= 1) v += __shfl_down(v, off, 64);
    __syncthreads();                 // protect partial[] from previous use
    if ((threadIdx.x & 63) == 0) partial[threadIdx.x >> 6] = v;
    __syncthreads();
    float s = partial[0];
#pragma unroll
    for (int i = 1; i < 16; ++i) s += partial[i];
    return s;
}

__global__ void init_weights_kernel(float* __restrict__ w) {
    __shared__ float partial[16];
    const int tid = threadIdx.x;  // 1024 threads

    // ga: sigma 12, radius 48
    {
        float v = 0.f;
        if (tid < GA_N) { float t = (float)(tid - GA_R) * (1.0f / 12.0f); v = expf(-0.5f * t * t); }
        float s = block_sum_1024(v, partial);
        if (tid < GA_N) w[GA_OFF + tid] = v / s;
    }
    // gb: sigma sqrt(96^2-12^2)/16, radius 24
    {
        const float sb = sqrtf(96.f * 96.f - 12.f * 12.f) * (1.0f / 16.0f);
        float v = 0.f;
        if (tid < GB_N) { float t = (float)(tid - GB_R) / sb; v = expf(-0.5f * t * t); }
        float s = block_sum_1024(v, partial);
        if (tid < GB_N) w[GB_OFF + tid] = v / s;
    }
    // w1: sigma 4.2, radius 17
    {
        float v = 0.f;
        if (tid < K1n) { float t = (float)(tid - R1) * (1.0f / 4.2f); v = expf(-0.5f * t * t); }
        float s = block_sum_1024(v, partial);
        if (tid < K1n) w[W1_OFF + tid] = v / s;
    }
    // k2: sigma 96, radius 384 (fallback paths)
    {
        float v = 0.f;
        if (tid < K2n) { float t = (float)(tid - R2) * (1.0f / 96.0f); v = expf(-0.5f * t * t); }
        float s = block_sum_1024(v, partial);
        if (tid < K2n) w[K2_OFF + tid] = v / s;
        if (tid < 784) w[K2P_OFF + tid] = (tid < K2n) ? v / s : 0.f;
    }
}

// ---- Stage A: d[b, jj+24, c] = sum_t ga[t] * x~[16*jj - 48 + t], jj in [-24,280]
// polyphase over p = t mod 16; 16 d-points per thread, streaming row window.
__global__ __launch_bounds__(256) void decimA_kernel(
        const float* __restrict__ x, const float* __restrict__ ga,
        float* __restrict__ d) {
    __shared__ float gs[GA_N];
    if (threadIdx.x < GA_N) gs[threadIdx.x] = ga[threadIdx.x];
    __syncthreads();

    const int lb = xcd_swizzle(blockIdx.x, gridDim.x);
    const int lin = lb * 256 + threadIdx.x;
    const int c = lin % Cdim;
    const int rest = lin / Cdim;
    const int g = rest % NGRP_A;
    const int b = rest / NGRP_A;
    if (b >= Bdim) return;

    const int jj0 = -24 + 16 * g;
    const float* xb = x + b * (Ldim * Cdim) + c;

    float acc[16];
#pragma unroll
    for (int ii = 0; ii < 16; ++ii) acc[ii] = 0.f;

    const bool interior = (jj0 >= 3) && (jj0 <= 237);

#pragma unroll 1
    for (int p = 0; p < 16; ++p) {
        float row[22];
        if (interior) {
            const float* xp = xb + (16 * (jj0 - 3) + p) * Cdim;
#pragma unroll
            for (int i = 0; i < 22; ++i) row[i] = xp[i * (16 * Cdim)];
        } else {
#pragma unroll
            for (int i = 0; i < 22; ++i)
                row[i] = xb[mirror_idx(16 * (jj0 - 3 + i) + p) * Cdim];
        }
#pragma unroll
        for (int q = 0; q < 6; ++q) {
            const float wq = gs[16 * q + p];
#pragma unroll
            for (int ii = 0; ii < 16; ++ii)
                acc[ii] = fmaf(wq, row[ii + q], acc[ii]);
        }
        if (p == 0) {  // tap t=96 exists only for phase 0
            const float w6 = gs[96];
#pragma unroll
            for (int ii = 0; ii < 16; ++ii)
                acc[ii] = fmaf(w6, row[ii + 6], acc[ii]);
        }
    }

    const int j0d = jj0 + 24;   // 0..304, multiple of 16
    float* db = d + (b * NJD + j0d) * Cdim + c;
#pragma unroll
    for (int ii = 0; ii < 16; ++ii)
        if (j0d + ii < NJD) db[ii * Cdim] = acc[ii];
}

// ---- Stage B: e[b, j, c] = sum_s gb[s] * d[b, j+s, c], j in [0,256]
// gather form: row window in registers, static acc indexing.
__global__ __launch_bounds__(256) void coarseB_kernel(
        const float* __restrict__ d, const float* __restrict__ gb,
        float* __restrict__ e) {
    __shared__ float gbs[GB_N];
    if (threadIdx.x < GB_N) gbs[threadIdx.x] = gb[threadIdx.x];
    __syncthreads();

    const int lin = blockIdx.x * 256 + threadIdx.x;
    const int c = lin % Cdim;
    const int rest = lin / Cdim;
    const int tj = rest % NTJ;
    const int b = rest / NTJ;
    if (b >= Bdim) return;

    const int j0 = tj * 8;
    const float* db = d + b * (NJD * Cdim) + c;

    float row[56];
#pragma unroll
    for (int r = 0; r < 56; ++r) {
        int idx = j0 + r;
        idx = idx > (NJD - 1) ? (NJD - 1) : idx;   // clamp for the tail group
        row[r] = db[idx * Cdim];
    }

    float acc[8];
#pragma unroll
    for (int jj = 0; jj < 8; ++jj) acc[jj] = 0.f;
#pragma unroll
    for (int s = 0; s < GB_N; ++s) {
        const float wv = gbs[s];
#pragma unroll
        for (int jj = 0; jj < 8; ++jj)
            acc[jj] = fmaf(wv, row[s + jj], acc[jj]);
    }

    float* eb = e + (b * NG + j0) * Cdim + c;
#pragma unroll
    for (int jj = 0; jj < 8; ++jj)
        if (j0 + jj < NG) eb[jj * Cdim] = acc[jj];
}

// ---- Stage C: narrow conv (exact) + linear interp of e + subtract.
// 32 outputs/thread, GATHER form (row[] preloaded, static indices everywhere).
__global__ __launch_bounds__(256, 2) void narrow_kernel(
        const float* __restrict__ x, const float* __restrict__ w1,
        const float* __restrict__ e, float* __restrict__ out) {
    __shared__ float ws[K1n];
    if (threadIdx.x < K1n) ws[threadIdx.x] = w1[threadIdx.x];
    __syncthreads();

    const int lb = xcd_swizzle(blockIdx.x, gridDim.x);
    const int lin = lb * 256 + threadIdx.x;
    const int c = lin % Cdim;
    const int rest = lin / Cdim;
    const int seg = rest % NSEG;
    const int b = rest / NSEG;
    if (b >= Bdim) return;

    const int l0 = seg * 32;
    const float* xb = x + b * (Ldim * Cdim) + c;

    // e loads (L3-resident), issued early
    const int j0 = seg * 2;
    const float* eb = e + (b * NG + j0) * Cdim + c;
    const float z0 = eb[0];
    const float z1 = eb[Cdim];
    const float z2 = eb[2 * Cdim];

    float row[66];
    if (seg >= 1 && seg <= 126) {
        const float* xp = xb + (l0 - R1) * Cdim;
#pragma unroll
        for (int i = 0; i < 66; ++i) row[i] = xp[i * Cdim];
    } else {
#pragma unroll
        for (int i = 0; i < 66; ++i)
            row[i] = xb[mirror_idx(l0 - R1 + i) * Cdim];
    }

    float acc[32];
#pragma unroll
    for (int m = 0; m < 32; ++m) acc[m] = 0.f;
#pragma unroll
    for (int t = 0; t < K1n; ++t) {
        const float wt = ws[t];   // LDS broadcast (wave-uniform)
#pragma unroll
        for (int m = 0; m < 32; ++m)
            acc[m] = fmaf(wt, row[t + m], acc[m]);
    }

    const float d0 = (z1 - z0) * (1.0f / 16.0f);
    const float d1 = (z2 - z1) * (1.0f / 16.0f);
    float* ob = out + (b * Ldim + l0) * Cdim + c;
#pragma unroll
    for (int m = 0; m < 16; ++m)
        ob[m * Cdim] = acc[m] - fmaf(d0, (float)m, z0);
#pragma unroll
    for (int m = 16; m < 32; ++m)
        ob[m * Cdim] = acc[m] - fmaf(d1, (float)(m - 16), z1);
}

// ---- Middle fallback: direct 769-tap wide conv on the stride-16 grid (round-1)
#define JPT 16
#define NJG 17
__global__ __launch_bounds__(256, 2) void wide_mid_kernel(
        const float* __restrict__ x, const float* __restrict__ w2p,
        float* __restrict__ z) {
    __shared__ float w2s[784];
    for (int i = threadIdx.x; i < 784; i += 256) w2s[i] = w2p[i];
    __syncthreads();

    const int gid = blockIdx.x * 256 + threadIdx.x;
    const int c = gid % Cdim;
    const int rest = gid / Cdim;
    const int jg = rest % NJG;
    const int b = rest / NJG;
    if (b >= Bdim) return;

    const int j0 = jg * JPT;
    const float* xb = x + b * (Ldim * Cdim) + c;

    float acc[JPT];
#pragma unroll
    for (int jj = 0; jj < JPT; ++jj) acc[jj] = 0.f;

    const bool interior = (j0 >= 24) && (16 * (j0 + 39) + 15 <= Ldim - 1);

#pragma unroll 1
    for (int p = 0; p < 16; ++p) {
        float row[64];
        if (interior) {
            const float* xp = xb + (16 * (j0 - 24) + p) * Cdim;
#pragma unroll
            for (int i = 0; i < 64; ++i) row[i] = xp[i * (16 * Cdim)];
        } else {
#pragma unroll
            for (int i = 0; i < 64; ++i)
                row[i] = xb[mirror_idx(16 * (j0 - 24 + i) + p) * Cdim];
        }
#pragma unroll
        for (int q = 0; q < 49; ++q) {
            const float wq = w2s[q * 16 + p];
#pragma unroll
            for (int jj = 0; jj < JPT; ++jj)
                acc[jj] = fmaf(wq, row[q + jj], acc[jj]);
        }
    }

    float* zb = z + (b * NG + j0) * Cdim + c;
#pragma unroll
    for (int jj = 0; jj < JPT; ++jj)
        if (j0 + jj < NG) zb[jj * Cdim] = acc[jj];
}

// ---- Last-resort fallback: fully direct
__global__ __launch_bounds__(256) void naive_kernel(
        const float* __restrict__ x, const float* __restrict__ w,
        float* __restrict__ out) {
    const int gid = blockIdx.x * 256 + threadIdx.x;
    if (gid >= Bdim * Ldim * Cdim) return;
    const int c = gid % Cdim;
    const int rest = gid / Cdim;
    const int l = rest % Ldim;
    const int b = rest / Ldim;
    const float* xb = x + b * (Ldim * Cdim) + c;
    float a2 = 0.f, a1 = 0.f;
    for (int t = 0; t < K2n; ++t)
        a2 = fmaf(w[K2_OFF + t], xb[mirror_idx(l + t - R2) * Cdim], a2);
#pragma unroll
    for (int t = 0; t < K1n; ++t)
        a1 = fmaf(w[W1_OFF + t], xb[mirror_idx(l + t - R1) * Cdim], a1);
    out[gid] = a1 - a2;
}

extern "C" void kernel_launch(void* const* d_in, const int* in_sizes, int n_in,
                              void* d_out, int out_size, void* d_ws, size_t ws_size,
                              hipStream_t stream) {
    (void)in_sizes; (void)n_in; (void)out_size;
    const float* x = (const float*)d_in[0];
    float* out = (float*)d_out;
    float* w = (float*)d_ws;

    hipLaunchKernelGGL(init_weights_kernel, dim3(1), dim3(1024), 0, stream, w);

    const size_t need_pyr = (size_t)WS_TOT * sizeof(float);
    const size_t need_mid = (size_t)(E2_OFF + Bdim * NG * Cdim) * sizeof(float);

    const int nar_total = Bdim * NSEG * Cdim;          // 1,314,816
    const dim3 nar_grid((nar_total + 255) / 256);

    if (ws_size >= need_pyr) {
        const int a_total = Bdim * NGRP_A * Cdim;      // 205,440
        hipLaunchKernelGGL(decimA_kernel, dim3((a_total + 255) / 256), dim3(256),
                           0, stream, x, w + GA_OFF, w + D_OFF);
        const int b_total = Bdim * NTJ * Cdim;         // 338,976
        hipLaunchKernelGGL(coarseB_kernel, dim3((b_total + 255) / 256), dim3(256),
                           0, stream, w + D_OFF, w + GB_OFF, w + E_OFF);
        hipLaunchKernelGGL(narrow_kernel, nar_grid, dim3(256),
                           0, stream, x, w + W1_OFF, w + E_OFF, out);
    } else if (ws_size >= need_mid) {
        const int wide_total = Bdim * NJG * Cdim;      // 174,624
        hipLaunchKernelGGL(wide_mid_kernel, dim3((wide_total + 255) / 256), dim3(256),
                           0, stream, x, w + K2P_OFF, w + E2_OFF);
        hipLaunchKernelGGL(narrow_kernel, nar_grid, dim3(256),
                           0, stream, x, w + W1_OFF, w + E2_OFF, out);
    } else {
        const int total = Bdim * Ldim * Cdim;
        hipLaunchKernelGGL(naive_kernel, dim3((total + 255) / 256), dim3(256),
                           0, stream, x, w, out);
    }
}